// Round 13
// baseline (195.684 us; speedup 1.0000x reference)
//
#include <hip/hip_runtime.h>
#include <math.h>

// Problem constants (fixed by setup_inputs)
#define BB 256      // batch
#define TT 256      // time steps
#define NQ 1000     // num_q
#define DK 128
#define DV 128
#define CC 32

typedef short s16x8 __attribute__((ext_vector_type(8)));   // 8 bf16 bit-patterns
typedef float f32x4 __attribute__((ext_vector_type(4)));
typedef float f32x2 __attribute__((ext_vector_type(2)));

__device__ __forceinline__ float fast_sigmoid(float x) {
    x = fminf(fmaxf(x, -30.f), 30.f);
    return 1.f / (1.f + __expf(-x));
}
__device__ __forceinline__ float fast_tanh(float x) {
    x = fminf(fmaxf(x, -15.f), 15.f);
    float t = __expf(2.f * x);
    return (t - 1.f) / (t + 1.f);
}
__device__ __forceinline__ unsigned short f2bf(float f) {   // RNE fp32->bf16
    unsigned u = __float_as_uint(f);
    u += 0x7fffu + ((u >> 16) & 1u);
    return (unsigned short)(u >> 16);
}
__device__ __forceinline__ float bf2f(unsigned short h) {
    return __uint_as_float((unsigned)h << 16);
}
__device__ __forceinline__ unsigned u4get(uint4 v, int i) { // i constant after unroll
    return i == 0 ? v.x : i == 1 ? v.y : i == 2 ? v.z : v.w;
}
__device__ __forceinline__ f32x2 mk2(float x, float y) { f32x2 r; r.x = x; r.y = y; return r; }
__device__ __forceinline__ f32x2 fma2(f32x2 a, f32x2 b, f32x2 c) {
    return __builtin_elementwise_fma(a, b, c);
}
__device__ __forceinline__ s16x8 cvt8(float4 v0, float4 v1) {
    s16x8 f;
    f[0] = (short)f2bf(v0.x); f[1] = (short)f2bf(v0.y);
    f[2] = (short)f2bf(v0.z); f[3] = (short)f2bf(v0.w);
    f[4] = (short)f2bf(v1.x); f[5] = (short)f2bf(v1.y);
    f[6] = (short)f2bf(v1.z); f[7] = (short)f2bf(v1.w);
    return f;
}

// ---------------------------------------------------------------------------
// conv_kernel: build bf16 TRANSPOSED weights in ws (B-operand layout Wt[n][k])
// ---------------------------------------------------------------------------
__global__ __launch_bounds__(256) void conv_kernel(
    const float* __restrict__ eW, const float* __restrict__ aW,
    const float* __restrict__ fW, const float* __restrict__ Mk,
    unsigned short* __restrict__ eWt, unsigned short* __restrict__ aWt,
    unsigned short* __restrict__ fWat, unsigned short* __restrict__ fWbt,
    unsigned short* __restrict__ Mkt)
{
    int idx = blockIdx.x * 256 + threadIdx.x;
    if (idx < 16384) {
        int n = idx >> 7, k = idx & 127;
        eWt[idx] = f2bf(eW[k * 128 + n]);
    } else if (idx < 32768) {
        int i = idx - 16384; int n = i >> 7, k = i & 127;
        aWt[i] = f2bf(aW[k * 128 + n]);
    } else if (idx < 49152) {
        int i = idx - 32768; int n = i >> 7, k = i & 127;
        fWat[i] = f2bf(fW[k * 128 + n]);
    } else if (idx < 65536) {
        int i = idx - 49152; int n = i >> 7, k = i & 127;
        fWbt[i] = f2bf(fW[(128 + k) * 128 + n]);
    } else if (idx < 69632) {
        int i = idx - 65536; int n = i >> 7, k = i & 127;   // n=c 0..31
        Mkt[i] = f2bf(Mk[k * 32 + n]);
    }
}

// ---------------------------------------------------------------------------
// pre_kernel v3 (R13): ZERO LDS, ZERO barriers. Each wave independently
// handles 16 rows. B-fragments are loaded DIRECTLY FROM GLOBAL (weights are
// 128 KB total, L2/L3-resident, reused by all 4096 waves) — deletes the 4
// weight stagings + 7 barriers per block that dominated pre. 16 waves/CU of
// free-running TLP hides all load latency.
// ---------------------------------------------------------------------------
__global__ __launch_bounds__(256) void pre_kernel(
    const int* __restrict__ skills, const int* __restrict__ responses,
    const float* __restrict__ k_emb, const float* __restrict__ v_emb,
    const float* __restrict__ fb, const float* __restrict__ eb,
    const float* __restrict__ ab,
    const unsigned short* __restrict__ Mkt, const unsigned short* __restrict__ fWbt,
    const unsigned short* __restrict__ eWt, const unsigned short* __restrict__ aWt,
    float* __restrict__ Wo, unsigned* __restrict__ EA,
    unsigned short* __restrict__ Ko, float* __restrict__ outTrue,
    int t0, int Tc)
{
    const int tid = threadIdx.x;
    const int lane = tid & 63;
    const int mrow = lane & 15, quad = lane >> 4;
    const size_t wbase = (size_t)blockIdx.x * 64 + (size_t)(tid >> 6) * 16;

    // per-lane gather row (A-side): row = wbase + mrow
    int grow = (int)wbase + mrow;
    int gb = grow / Tc;
    int gt = t0 + (grow - gb * Tc);
    int gi = gb * TT + gt;
    int s = skills[gi];
    int r = responses[gi];
    int q = s + NQ * ((r > -1) ? r : 0);
    if (quad == 0 && gt >= 1) outTrue[gb * (TT - 1) + (gt - 1)] = (float)r;

    // kt A-frags direct from global
    s16x8 aF[4];
    {
        const float* kr = k_emb + (size_t)s * DK + quad * 8;
#pragma unroll
        for (int kb = 0; kb < 4; ++kb)
            aF[kb] = cvt8(*(const float4*)(kr + kb * 32),
                          *(const float4*)(kr + kb * 32 + 4));
    }

    // logits (NT=2, B direct from Mkt global) + in-register softmax -> Wo
    {
        f32x4 l0 = {0.f, 0.f, 0.f, 0.f}, l1 = {0.f, 0.f, 0.f, 0.f};
#pragma unroll
        for (int kb = 0; kb < 4; ++kb) {
            s16x8 b0 = *(const s16x8*)&Mkt[mrow * 128 + kb * 32 + quad * 8];
            s16x8 b1 = *(const s16x8*)&Mkt[(16 + mrow) * 128 + kb * 32 + quad * 8];
            l0 = __builtin_amdgcn_mfma_f32_16x16x32_bf16(aF[kb], b0, l0, 0, 0, 0);
            l1 = __builtin_amdgcn_mfma_f32_16x16x32_bf16(aF[kb], b1, l1, 0, 0, 0);
        }
#pragma unroll
        for (int reg = 0; reg < 4; ++reg) {
            float a0 = l0[reg], a1 = l1[reg];
            float m = fmaxf(a0, a1);
#pragma unroll
            for (int off = 1; off < 16; off <<= 1)
                m = fmaxf(m, __shfl_xor(m, off, 64));
            float e0 = __expf(a0 - m), e1 = __expf(a1 - m);
            float ssum = e0 + e1;
#pragma unroll
            for (int off = 1; off < 16; off <<= 1)
                ssum += __shfl_xor(ssum, off, 64);
            float inv = 1.f / ssum;
            size_t rowg = wbase + quad * 4 + reg;
            Wo[rowg * 32 + mrow]      = e0 * inv;
            Wo[rowg * 32 + 16 + mrow] = e1 * inv;
        }
    }

    // vt A-frags direct from global
    s16x8 vF[4];
    {
        const float* vr = v_emb + (size_t)q * DV + quad * 8;
#pragma unroll
        for (int kb = 0; kb < 4; ++kb)
            vF[kb] = cvt8(*(const float4*)(vr + kb * 32),
                          *(const float4*)(vr + kb * 32 + 4));
    }

    // ck = kt@fWb + fb -> Ko (B direct from fWbt global)
#pragma unroll
    for (int nt = 0; nt < 8; ++nt) {
        f32x4 acc = {0.f, 0.f, 0.f, 0.f};
#pragma unroll
        for (int kb = 0; kb < 4; ++kb) {
            s16x8 bf = *(const s16x8*)&fWbt[(nt * 16 + mrow) * 128 + kb * 32 + quad * 8];
            acc = __builtin_amdgcn_mfma_f32_16x16x32_bf16(aF[kb], bf, acc, 0, 0, 0);
        }
        int col = nt * 16 + mrow;
        float fbv = fb[col];
#pragma unroll
        for (int reg = 0; reg < 4; ++reg) {
            size_t rr = wbase + quad * 4 + reg;
            Ko[rr * 128 + col] = f2bf(acc[reg] + fbv);
        }
    }

    // et = sigmoid(vt@eW + eb) -> registers (B direct from eWt global)
    float etr[8][4];
#pragma unroll
    for (int nt = 0; nt < 8; ++nt) {
        f32x4 acc = {0.f, 0.f, 0.f, 0.f};
#pragma unroll
        for (int kb = 0; kb < 4; ++kb) {
            s16x8 bf = *(const s16x8*)&eWt[(nt * 16 + mrow) * 128 + kb * 32 + quad * 8];
            acc = __builtin_amdgcn_mfma_f32_16x16x32_bf16(vF[kb], bf, acc, 0, 0, 0);
        }
        int col = nt * 16 + mrow;
        float ebv = eb[col];
#pragma unroll
        for (int reg = 0; reg < 4; ++reg)
            etr[nt][reg] = fast_sigmoid(acc[reg] + ebv);
    }

    // at = tanh(vt@aW + ab); pack (et,at) -> EA (B direct from aWt global)
#pragma unroll
    for (int nt = 0; nt < 8; ++nt) {
        f32x4 acc = {0.f, 0.f, 0.f, 0.f};
#pragma unroll
        for (int kb = 0; kb < 4; ++kb) {
            s16x8 bf = *(const s16x8*)&aWt[(nt * 16 + mrow) * 128 + kb * 32 + quad * 8];
            acc = __builtin_amdgcn_mfma_f32_16x16x32_bf16(vF[kb], bf, acc, 0, 0, 0);
        }
        int col = nt * 16 + mrow;
        float abv = ab[col];
#pragma unroll
        for (int reg = 0; reg < 4; ++reg) {
            size_t rr = wbase + quad * 4 + reg;
            int bb = (int)(rr / (size_t)Tc);
            int t  = (int)(rr - (size_t)bb * Tc);
            size_t o4 = (((size_t)bb * (Tc >> 5) + (t >> 5)) * 8 + ((t >> 2) & 7)) * 128 + col;
            unsigned lo = f2bf(etr[nt][reg]);
            unsigned hi = (unsigned)f2bf(fast_tanh(acc[reg] + abv)) << 16;
            EA[o4 * 4 + (t & 3)] = hi | lo;
        }
    }
}

// ---------------------------------------------------------------------------
// fused_kernel v5 (seq + post) — EXACT R11 form (proven 54.7 us). R12's
// scalar-load attempt regressed (compiler won't scalarize VALU-feeding
// loads; FETCH +4 MB, at-use L2 latency). w stays on the LDS broadcast path.
// ---------------------------------------------------------------------------

#define CH 32
#define WROW 36     // Wl row stride (floats)
#define RSTR 136    // rtl/fWl row stride (shorts)
#define SB() __builtin_amdgcn_sched_barrier(0)

#define LOAD_W(gg) do {                                                       \
    const float* ws = Wb + (size_t)(gg) * CH * 32;                            \
    wr0 = *(const float4*)(ws + tid * 8);                                     \
    wr1 = *(const float4*)(ws + tid * 8 + 4);                                 \
} while (0)

#define PUB_W(gg) do {                                                        \
    float* wd = &Wl[(gg) & 1][lr * WROW + lq * 8];                            \
    *(float4*)wd = wr0; *(float4*)(wd + 4) = wr1;                             \
} while (0)

#define LOAD_EA(ER, gg) do {                                                  \
    const uint4* src = EA4 + ((size_t)(bq + (gg))) * 1024 + tid;              \
    _Pragma("unroll")                                                         \
    for (int j = 0; j < 8; ++j) ER[j] = src[j * 128];                         \
} while (0)

#define PREF8(A0,A1,A2,A3,A4,A5,A6,A7, rowidx) do {                           \
    const float* _wr = wlc + (rowidx) * WROW;                                 \
    A0 = *(const float4*)(_wr + 0);  A1 = *(const float4*)(_wr + 4);          \
    A2 = *(const float4*)(_wr + 8);  A3 = *(const float4*)(_wr + 12);         \
    A4 = *(const float4*)(_wr + 16); A5 = *(const float4*)(_wr + 20);         \
    A6 = *(const float4*)(_wr + 24); A7 = *(const float4*)(_wr + 28);         \
} while (0)

#define STEP8(A0,A1,A2,A3,A4,A5,A6,A7, ER, tl) do {                           \
    f32x2 w2[16];                                                             \
    w2[0]  = mk2(A0.x, A0.y); w2[1]  = mk2(A0.z, A0.w);                       \
    w2[2]  = mk2(A1.x, A1.y); w2[3]  = mk2(A1.z, A1.w);                       \
    w2[4]  = mk2(A2.x, A2.y); w2[5]  = mk2(A2.z, A2.w);                       \
    w2[6]  = mk2(A3.x, A3.y); w2[7]  = mk2(A3.z, A3.w);                       \
    w2[8]  = mk2(A4.x, A4.y); w2[9]  = mk2(A4.z, A4.w);                       \
    w2[10] = mk2(A5.x, A5.y); w2[11] = mk2(A5.z, A5.w);                       \
    w2[12] = mk2(A6.x, A6.y); w2[13] = mk2(A6.z, A6.w);                       \
    w2[14] = mk2(A7.x, A7.y); w2[15] = mk2(A7.z, A7.w);                       \
    unsigned ea = u4get(ER[(tl) >> 2], (tl) & 3);                             \
    float e = __uint_as_float(ea << 16);                                      \
    float a = __uint_as_float(ea & 0xffff0000u);                              \
    f32x2 ne2 = mk2(-e, -e);                                                  \
    f32x2 a2  = mk2(a, a);                                                    \
    f32x2 r0 = mk2(0.f, 0.f), r1 = r0, r2 = r0, r3 = r0;                      \
    _Pragma("unroll")                                                         \
    for (int q = 0; q < 4; ++q) {                                             \
        r0 = fma2(w2[4*q+0], Mv2[4*q+0], r0);                                 \
        r1 = fma2(w2[4*q+1], Mv2[4*q+1], r1);                                 \
        r2 = fma2(w2[4*q+2], Mv2[4*q+2], r2);                                 \
        r3 = fma2(w2[4*q+3], Mv2[4*q+3], r3);                                 \
    }                                                                         \
    f32x2 rs = (r0 + r1) + (r2 + r3);                                         \
    slp[(tl) * RSTR + tid] = f2bf(rs.x + rs.y);                               \
    _Pragma("unroll")                                                         \
    for (int i = 0; i < 16; ++i)                                              \
        Mv2[i] = fma2(w2[i], fma2(ne2, Mv2[i], a2), Mv2[i]);                  \
} while (0)

#define SEQ_CHUNK(ER, gg, SL) do {                                            \
    const float* wlc = Wl[(gg) & 1];                                          \
    unsigned short* slp = SL;                                                 \
    PREF8(w0,w1,w2_,w3_,w4_,w5_,w6_,w7_, 0);                                  \
    _Pragma("unroll")                                                         \
    for (int tp = 0; tp < 16; ++tp) {                                         \
        SB(); PREF8(u0,u1,u2,u3,u4,u5,u6,u7, 2 * tp + 1); SB();               \
        STEP8(w0,w1,w2_,w3_,w4_,w5_,w6_,w7_, ER, 2 * tp);                     \
        SB(); PREF8(w0,w1,w2_,w3_,w4_,w5_,w6_,w7_,                            \
                    (2 * tp + 2 < 32) ? (2 * tp + 2) : 31); SB();             \
        STEP8(u0,u1,u2,u3,u4,u5,u6,u7, ER, 2 * tp + 1);                       \
    }                                                                         \
} while (0)

__device__ __forceinline__ void consume_chunk(
    int gc, const unsigned short* sl, const unsigned short* fWl,
    int b, int Tc, int t0,
    const unsigned short* __restrict__ Ko, const float* __restrict__ pW,
    float pbv, float* __restrict__ pred, int tid)
{
    const int lane = tid & 63;
    const int cw = (tid >> 6) & 1;          // consumer wave 0/1 -> rows cw*16..+15
    const int mrow = lane & 15, quad = lane >> 4;
    s16x8 aF[4];
#pragma unroll
    for (int kb = 0; kb < 4; ++kb)
        aF[kb] = *(const s16x8*)&sl[(cw * 16 + mrow) * RSTR + kb * 32 + quad * 8];
    float p0 = 0.f, p1 = 0.f, p2 = 0.f, p3 = 0.f;
    size_t rbase = (size_t)b * Tc + gc * CH + cw * 16 + quad * 4;
#pragma unroll
    for (int nt = 0; nt < 8; ++nt) {
        f32x4 acc = {0.f, 0.f, 0.f, 0.f};
#pragma unroll
        for (int kb = 0; kb < 4; ++kb) {
            s16x8 bf = *(const s16x8*)&fWl[(nt * 16 + mrow) * RSTR + kb * 32 + quad * 8];
            acc = __builtin_amdgcn_mfma_f32_16x16x32_bf16(aF[kb], bf, acc, 0, 0, 0);
        }
        int col = nt * 16 + mrow;
        float pw = pW[col];
        p0 = fmaf(fast_tanh(acc[0] + bf2f(Ko[(rbase + 0) * 128 + col])), pw, p0);
        p1 = fmaf(fast_tanh(acc[1] + bf2f(Ko[(rbase + 1) * 128 + col])), pw, p1);
        p2 = fmaf(fast_tanh(acc[2] + bf2f(Ko[(rbase + 2) * 128 + col])), pw, p2);
        p3 = fmaf(fast_tanh(acc[3] + bf2f(Ko[(rbase + 3) * 128 + col])), pw, p3);
    }
#pragma unroll
    for (int off = 1; off < 16; off <<= 1) {
        p0 += __shfl_xor(p0, off, 64); p1 += __shfl_xor(p1, off, 64);
        p2 += __shfl_xor(p2, off, 64); p3 += __shfl_xor(p3, off, 64);
    }
    if (mrow == 0) {
        int tb = t0 + gc * CH + cw * 16 + quad * 4;
        float ps[4] = {p0, p1, p2, p3};
#pragma unroll
        for (int reg = 0; reg < 4; ++reg) {
            int t = tb + reg;
            if (t < TT - 1) pred[b * (TT - 1) + t] = fast_sigmoid(ps[reg] + pbv);
        }
    }
}

__global__ __launch_bounds__(256, 1) void fused_kernel(
    const float* __restrict__ W, const unsigned* __restrict__ EA,
    const float* __restrict__ Mv0, const unsigned short* __restrict__ Ko,
    const unsigned short* __restrict__ fWat, const float* __restrict__ pW,
    const float* __restrict__ pb,
    float* __restrict__ pred, float* __restrict__ MvWS,
    int t0, int Tc, int doInit, int doSave)
{
    const int b = blockIdx.x;
    const int tid = threadIdx.x;
    const int nch = Tc / CH;

    __shared__ __align__(16) float Wl[2][CH * WROW];            //  9.2 KB
    __shared__ __align__(16) unsigned short rtl[2][CH * RSTR];  // 17.4 KB
    __shared__ __align__(16) unsigned short fWl[128 * RSTR];    // 34.8 KB

    // stage fWat -> fWl (all 256 threads)
    {
        int n = tid >> 1, k0 = (tid & 1) * 64;
#pragma unroll
        for (int j = 0; j < 8; ++j)
            *(s16x8*)&fWl[n * RSTR + k0 + j * 8] = *(const s16x8*)&fWat[n * 128 + k0 + j * 8];
    }

    const int lr = tid >> 2, lq = tid & 3;
    const float* __restrict__ Wb = W + (size_t)b * Tc * 32;
    const uint4* __restrict__ EA4 = (const uint4*)EA;
    const int bq = b * nch;
    f32x2 Mv2[16];
    float4 wr0, wr1;
    float4 w0, w1, w2_, w3_, w4_, w5_, w6_, w7_;
    float4 u0, u1, u2, u3, u4, u5, u6, u7;
    uint4 erA[8], erB[8];
    float pbv = 0.f;

    if (tid < 128) {
        if (doInit) {
#pragma unroll
            for (int i = 0; i < 16; ++i)
                Mv2[i] = mk2(Mv0[(2 * i) * 128 + tid], Mv0[(2 * i + 1) * 128 + tid]);
        } else {
#pragma unroll
            for (int i = 0; i < 16; ++i)
                Mv2[i] = mk2(MvWS[(size_t)b * 4096 + (2 * i) * 128 + tid],
                             MvWS[(size_t)b * 4096 + (2 * i + 1) * 128 + tid]);
        }
        LOAD_W(0); PUB_W(0);
        LOAD_EA(erA, 0);
        if (nch > 1) LOAD_W(1);
    } else {
        pbv = pb[0];
    }
    __syncthreads();

    for (int g = 0; g < nch; g += 2) {
        // ---- even chunk g: produce -> slot0; consume chunk g-1 (slot1) ----
        if (tid < 128) {
            if (g + 1 < nch) PUB_W(g + 1);
            if (g + 2 < nch) LOAD_W(g + 2);
            if (g + 1 < nch) LOAD_EA(erB, g + 1);
            SEQ_CHUNK(erA, g, rtl[0]);
        } else if (g >= 1) {
            consume_chunk(g - 1, rtl[1], fWl, b, Tc, t0, Ko, pW, pbv, pred, tid);
        }
        __syncthreads();

        // ---- odd chunk g+1: produce -> slot1; consume chunk g (slot0) ----
        if (tid < 128) {
            if (g + 1 < nch) {
                if (g + 2 < nch) PUB_W(g + 2);
                if (g + 3 < nch) LOAD_W(g + 3);
                if (g + 2 < nch) LOAD_EA(erA, g + 2);
                SEQ_CHUNK(erB, g + 1, rtl[1]);
            }
        } else {
            consume_chunk(g, rtl[0], fWl, b, Tc, t0, Ko, pW, pbv, pred, tid);
        }
        __syncthreads();
    }
    // epilogue: for even nch the last (odd) chunk is still unconsumed
    if (!(nch & 1) && tid >= 128) {
        consume_chunk(nch - 1, rtl[1], fWl, b, Tc, t0, Ko, pW, pbv, pred, tid);
    }

    if (doSave && tid < 128) {
#pragma unroll
        for (int i = 0; i < 16; ++i) {
            MvWS[(size_t)b * 4096 + (2 * i) * 128 + tid]     = Mv2[i].x;
            MvWS[(size_t)b * 4096 + (2 * i + 1) * 128 + tid] = Mv2[i].y;
        }
    }
}

// ---------------------------------------------------------------------------

extern "C" void kernel_launch(void* const* d_in, const int* in_sizes, int n_in,
                              void* d_out, int out_size, void* d_ws, size_t ws_size,
                              hipStream_t stream) {
    const int*   skills    = (const int*)d_in[0];
    const int*   responses = (const int*)d_in[1];
    const float* k_emb     = (const float*)d_in[2];
    const float* v_emb     = (const float*)d_in[3];
    const float* Mk        = (const float*)d_in[4];
    const float* Mv0       = (const float*)d_in[5];
    const float* f_W       = (const float*)d_in[6];
    const float* f_b       = (const float*)d_in[7];
    const float* p_W       = (const float*)d_in[8];
    const float* p_b       = (const float*)d_in[9];
    const float* e_W       = (const float*)d_in[10];
    const float* e_b       = (const float*)d_in[11];
    const float* a_W       = (const float*)d_in[12];
    const float* a_b       = (const float*)d_in[13];

    float* pred    = (float*)d_out;                 // [256][255]
    float* outTrue = pred + BB * (TT - 1);          // [256][255]

    // scratch per row: Wo 128 B + EA 512 B + Ko 256 B = 896 B
    int Tc = TT;
    for (;;) {
        size_t need = (size_t)BB * Tc * 896 + 69632 * 2;
        if (Tc < TT) need += (size_t)BB * 4096 * 4;
        if (need <= ws_size || Tc <= 32) break;
        Tc >>= 1;
    }

    char* p = (char*)d_ws;
    float* Wo = (float*)p;                     p += (size_t)BB * Tc * 32 * 4;
    unsigned* EA = (unsigned*)p;               p += (size_t)BB * Tc * 128 * 4;
    unsigned short* Ko = (unsigned short*)p;   p += (size_t)BB * Tc * 128 * 2;
    unsigned short* eWt = (unsigned short*)p;  p += 16384 * 2;
    unsigned short* aWt = (unsigned short*)p;  p += 16384 * 2;
    unsigned short* fWat = (unsigned short*)p; p += 16384 * 2;
    unsigned short* fWbt = (unsigned short*)p; p += 16384 * 2;
    unsigned short* Mkt = (unsigned short*)p;  p += 4096 * 2;
    float* MvWS = (float*)p;

    conv_kernel<<<272, 256, 0, stream>>>(e_W, a_W, f_W, Mk,
                                         eWt, aWt, fWat, fWbt, Mkt);

    for (int t0 = 0; t0 < TT; t0 += Tc) {
        pre_kernel<<<(BB * Tc) / 64, 256, 0, stream>>>(
            skills, responses, k_emb, v_emb, f_b, e_b, a_b,
            Mkt, fWbt, eWt, aWt, Wo, EA, Ko, outTrue, t0, Tc);
        fused_kernel<<<BB, 256, 0, stream>>>(
            Wo, EA, Mv0, Ko, fWat, p_W, p_b, pred, MvWS,
            t0, Tc, t0 == 0 ? 1 : 0, (t0 + Tc < TT) ? 1 : 0);
    }
}

// Round 14
// 180.819 us; speedup vs baseline: 1.0822x; 1.0822x over previous
//
#include <hip/hip_runtime.h>
#include <math.h>

// Problem constants (fixed by setup_inputs)
#define BB 256      // batch
#define TT 256      // time steps
#define NQ 1000     // num_q
#define DK 128
#define DV 128
#define CC 32

typedef short s16x8 __attribute__((ext_vector_type(8)));   // 8 bf16 bit-patterns
typedef float f32x4 __attribute__((ext_vector_type(4)));
typedef float f32x2 __attribute__((ext_vector_type(2)));

__device__ __forceinline__ float fast_sigmoid(float x) {
    x = fminf(fmaxf(x, -30.f), 30.f);
    return 1.f / (1.f + __expf(-x));
}
__device__ __forceinline__ float fast_tanh(float x) {
    x = fminf(fmaxf(x, -15.f), 15.f);
    float t = __expf(2.f * x);
    return (t - 1.f) / (t + 1.f);
}
__device__ __forceinline__ unsigned short f2bf(float f) {   // RNE fp32->bf16
    unsigned u = __float_as_uint(f);
    u += 0x7fffu + ((u >> 16) & 1u);
    return (unsigned short)(u >> 16);
}
__device__ __forceinline__ float bf2f(unsigned short h) {
    return __uint_as_float((unsigned)h << 16);
}
__device__ __forceinline__ unsigned u4get(uint4 v, int i) { // i constant after unroll
    return i == 0 ? v.x : i == 1 ? v.y : i == 2 ? v.z : v.w;
}
__device__ __forceinline__ f32x2 mk2(float x, float y) { f32x2 r; r.x = x; r.y = y; return r; }
__device__ __forceinline__ f32x2 fma2(f32x2 a, f32x2 b, f32x2 c) {
    return __builtin_elementwise_fma(a, b, c);
}
__device__ __forceinline__ s16x8 cvt8(float4 v0, float4 v1) {
    s16x8 f;
    f[0] = (short)f2bf(v0.x); f[1] = (short)f2bf(v0.y);
    f[2] = (short)f2bf(v0.z); f[3] = (short)f2bf(v0.w);
    f[4] = (short)f2bf(v1.x); f[5] = (short)f2bf(v1.y);
    f[6] = (short)f2bf(v1.z); f[7] = (short)f2bf(v1.w);
    return f;
}

// ---------------------------------------------------------------------------
// conv_kernel: build bf16 TRANSPOSED weights in ws (B-operand layout Wt[n][k])
// ---------------------------------------------------------------------------
__global__ __launch_bounds__(256) void conv_kernel(
    const float* __restrict__ eW, const float* __restrict__ aW,
    const float* __restrict__ fW, const float* __restrict__ Mk,
    unsigned short* __restrict__ eWt, unsigned short* __restrict__ aWt,
    unsigned short* __restrict__ fWat, unsigned short* __restrict__ fWbt,
    unsigned short* __restrict__ Mkt)
{
    int idx = blockIdx.x * 256 + threadIdx.x;
    if (idx < 16384) {
        int n = idx >> 7, k = idx & 127;
        eWt[idx] = f2bf(eW[k * 128 + n]);
    } else if (idx < 32768) {
        int i = idx - 16384; int n = i >> 7, k = i & 127;
        aWt[i] = f2bf(aW[k * 128 + n]);
    } else if (idx < 49152) {
        int i = idx - 32768; int n = i >> 7, k = i & 127;
        fWat[i] = f2bf(fW[k * 128 + n]);
    } else if (idx < 65536) {
        int i = idx - 49152; int n = i >> 7, k = i & 127;
        fWbt[i] = f2bf(fW[(128 + k) * 128 + n]);
    } else if (idx < 69632) {
        int i = idx - 65536; int n = i >> 7, k = i & 127;   // n=c 0..31
        Mkt[i] = f2bf(Mk[k * 32 + n]);
    }
}

// ---------------------------------------------------------------------------
// pre_kernel v2 (EXACT R11 revert — proven ~37 us): Wlds staging + direct-to-
// fragment gathers + in-register softmax + et parked in registers.
// R13's LDS-free variant regressed to 69 us (at-use global B-frag latency
// serialized the MFMA chains) — staged LDS B-frags win here.
// ---------------------------------------------------------------------------
__global__ __launch_bounds__(256) void pre_kernel(
    const int* __restrict__ skills, const int* __restrict__ responses,
    const float* __restrict__ k_emb, const float* __restrict__ v_emb,
    const float* __restrict__ fb, const float* __restrict__ eb,
    const float* __restrict__ ab,
    const unsigned short* __restrict__ Mkt, const unsigned short* __restrict__ fWbt,
    const unsigned short* __restrict__ eWt, const unsigned short* __restrict__ aWt,
    float* __restrict__ Wo, unsigned* __restrict__ EA,
    unsigned short* __restrict__ Ko, float* __restrict__ outTrue,
    int t0, int Tc)
{
    const int tid = threadIdx.x;
    const int lane = tid & 63;
    const int m_base = (tid >> 6) * 16;
    const int mrow = lane & 15, quad = lane >> 4;
    const size_t base = (size_t)blockIdx.x * 64;

    __shared__ __align__(16) unsigned short Wlds[128 * 136];   // 34.8 KB

    int grow = (int)base + m_base + mrow;
    int gb = grow / Tc;
    int gt = t0 + (grow - gb * Tc);
    int gi = gb * TT + gt;
    int s = skills[gi];
    int r = responses[gi];
    int q = s + NQ * ((r > -1) ? r : 0);
    if (quad == 0 && gt >= 1) outTrue[gb * (TT - 1) + (gt - 1)] = (float)r;

    {
        int n = tid >> 3, k0 = (tid & 7) * 16;
        *(s16x8*)&Wlds[n * 136 + k0]     = *(const s16x8*)&Mkt[n * 128 + k0];
        *(s16x8*)&Wlds[n * 136 + k0 + 8] = *(const s16x8*)&Mkt[n * 128 + k0 + 8];
    }

    s16x8 aF[4];
    {
        const float* kr = k_emb + (size_t)s * DK + quad * 8;
#pragma unroll
        for (int kb = 0; kb < 4; ++kb)
            aF[kb] = cvt8(*(const float4*)(kr + kb * 32),
                          *(const float4*)(kr + kb * 32 + 4));
    }
    __syncthreads();   // [1]

    {
        f32x4 l0 = {0.f, 0.f, 0.f, 0.f}, l1 = {0.f, 0.f, 0.f, 0.f};
#pragma unroll
        for (int kb = 0; kb < 4; ++kb) {
            s16x8 b0 = *(const s16x8*)&Wlds[mrow * 136 + kb * 32 + quad * 8];
            s16x8 b1 = *(const s16x8*)&Wlds[(16 + mrow) * 136 + kb * 32 + quad * 8];
            l0 = __builtin_amdgcn_mfma_f32_16x16x32_bf16(aF[kb], b0, l0, 0, 0, 0);
            l1 = __builtin_amdgcn_mfma_f32_16x16x32_bf16(aF[kb], b1, l1, 0, 0, 0);
        }
#pragma unroll
        for (int reg = 0; reg < 4; ++reg) {
            float a0 = l0[reg], a1 = l1[reg];
            float m = fmaxf(a0, a1);
#pragma unroll
            for (int off = 1; off < 16; off <<= 1)
                m = fmaxf(m, __shfl_xor(m, off, 64));
            float e0 = __expf(a0 - m), e1 = __expf(a1 - m);
            float ssum = e0 + e1;
#pragma unroll
            for (int off = 1; off < 16; off <<= 1)
                ssum += __shfl_xor(ssum, off, 64);
            float inv = 1.f / ssum;
            size_t rowg = base + m_base + quad * 4 + reg;
            Wo[rowg * 32 + mrow]      = e0 * inv;
            Wo[rowg * 32 + 16 + mrow] = e1 * inv;
        }
    }
    __syncthreads();   // [2]

    {
        int n = tid >> 1, k0 = (tid & 1) * 64;
#pragma unroll
        for (int j = 0; j < 8; ++j)
            *(s16x8*)&Wlds[n * 136 + k0 + j * 8] = *(const s16x8*)&fWbt[n * 128 + k0 + j * 8];
    }
    __syncthreads();   // [3]

    s16x8 vF[4];
    {
        const float* vr = v_emb + (size_t)q * DV + quad * 8;
#pragma unroll
        for (int kb = 0; kb < 4; ++kb)
            vF[kb] = cvt8(*(const float4*)(vr + kb * 32),
                          *(const float4*)(vr + kb * 32 + 4));
    }

#pragma unroll
    for (int nt = 0; nt < 8; ++nt) {
        f32x4 acc = {0.f, 0.f, 0.f, 0.f};
#pragma unroll
        for (int kb = 0; kb < 4; ++kb) {
            s16x8 bf = *(const s16x8*)&Wlds[(nt * 16 + mrow) * 136 + kb * 32 + quad * 8];
            acc = __builtin_amdgcn_mfma_f32_16x16x32_bf16(aF[kb], bf, acc, 0, 0, 0);
        }
        int col = nt * 16 + mrow;
        float fbv = fb[col];
#pragma unroll
        for (int reg = 0; reg < 4; ++reg) {
            size_t rr = base + m_base + quad * 4 + reg;
            Ko[rr * 128 + col] = f2bf(acc[reg] + fbv);
        }
    }
    __syncthreads();   // [4]

    {
        int n = tid >> 1, k0 = (tid & 1) * 64;
#pragma unroll
        for (int j = 0; j < 8; ++j)
            *(s16x8*)&Wlds[n * 136 + k0 + j * 8] = *(const s16x8*)&eWt[n * 128 + k0 + j * 8];
    }
    __syncthreads();   // [5]

    float etr[8][4];
#pragma unroll
    for (int nt = 0; nt < 8; ++nt) {
        f32x4 acc = {0.f, 0.f, 0.f, 0.f};
#pragma unroll
        for (int kb = 0; kb < 4; ++kb) {
            s16x8 bf = *(const s16x8*)&Wlds[(nt * 16 + mrow) * 136 + kb * 32 + quad * 8];
            acc = __builtin_amdgcn_mfma_f32_16x16x32_bf16(vF[kb], bf, acc, 0, 0, 0);
        }
        int col = nt * 16 + mrow;
        float ebv = eb[col];
#pragma unroll
        for (int reg = 0; reg < 4; ++reg)
            etr[nt][reg] = fast_sigmoid(acc[reg] + ebv);
    }
    __syncthreads();   // [6]

    {
        int n = tid >> 1, k0 = (tid & 1) * 64;
#pragma unroll
        for (int j = 0; j < 8; ++j)
            *(s16x8*)&Wlds[n * 136 + k0 + j * 8] = *(const s16x8*)&aWt[n * 128 + k0 + j * 8];
    }
    __syncthreads();   // [7]

#pragma unroll
    for (int nt = 0; nt < 8; ++nt) {
        f32x4 acc = {0.f, 0.f, 0.f, 0.f};
#pragma unroll
        for (int kb = 0; kb < 4; ++kb) {
            s16x8 bf = *(const s16x8*)&Wlds[(nt * 16 + mrow) * 136 + kb * 32 + quad * 8];
            acc = __builtin_amdgcn_mfma_f32_16x16x32_bf16(vF[kb], bf, acc, 0, 0, 0);
        }
        int col = nt * 16 + mrow;
        float abv = ab[col];
#pragma unroll
        for (int reg = 0; reg < 4; ++reg) {
            size_t rr = base + m_base + quad * 4 + reg;
            int bb = (int)(rr / (size_t)Tc);
            int t  = (int)(rr - (size_t)bb * Tc);
            size_t o4 = (((size_t)bb * (Tc >> 5) + (t >> 5)) * 8 + ((t >> 2) & 7)) * 128 + col;
            unsigned lo = f2bf(etr[nt][reg]);
            unsigned hi = (unsigned)f2bf(fast_tanh(acc[reg] + abv)) << 16;
            EA[o4 * 4 + (t & 3)] = hi | lo;
        }
    }
}

// ---------------------------------------------------------------------------
// fused_kernel v7 (seq + post) — R14:
//  Producer side byte-identical to R11 (proven 54.7 us). Consumer change:
//  fWl LDS buffer DELETED — consumer B-fragments read directly from fWat
//  global (32 KB, L2-resident). Consumers have ~8x slack per chunk window,
//  so the L2 latency is absorbed; what matters is that their ~8-way
//  conflicted LDS fragment reads (655K conflict cycles) stop stealing LDS
//  pipe from the latency-critical producer w-reads. LDS 61 -> 27 KB.
// ---------------------------------------------------------------------------

#define CH 32
#define WROW 36     // Wl row stride (floats)
#define RSTR 136    // rtl row stride (shorts)
#define SB() __builtin_amdgcn_sched_barrier(0)

#define LOAD_W(gg) do {                                                       \
    const float* ws = Wb + (size_t)(gg) * CH * 32;                            \
    wr0 = *(const float4*)(ws + tid * 8);                                     \
    wr1 = *(const float4*)(ws + tid * 8 + 4);                                 \
} while (0)

#define PUB_W(gg) do {                                                        \
    float* wd = &Wl[(gg) & 1][lr * WROW + lq * 8];                            \
    *(float4*)wd = wr0; *(float4*)(wd + 4) = wr1;                             \
} while (0)

#define LOAD_EA(ER, gg) do {                                                  \
    const uint4* src = EA4 + ((size_t)(bq + (gg))) * 1024 + tid;              \
    _Pragma("unroll")                                                         \
    for (int j = 0; j < 8; ++j) ER[j] = src[j * 128];                         \
} while (0)

#define PREF8(A0,A1,A2,A3,A4,A5,A6,A7, rowidx) do {                           \
    const float* _wr = wlc + (rowidx) * WROW;                                 \
    A0 = *(const float4*)(_wr + 0);  A1 = *(const float4*)(_wr + 4);          \
    A2 = *(const float4*)(_wr + 8);  A3 = *(const float4*)(_wr + 12);         \
    A4 = *(const float4*)(_wr + 16); A5 = *(const float4*)(_wr + 20);         \
    A6 = *(const float4*)(_wr + 24); A7 = *(const float4*)(_wr + 28);         \
} while (0)

#define STEP8(A0,A1,A2,A3,A4,A5,A6,A7, ER, tl) do {                           \
    f32x2 w2[16];                                                             \
    w2[0]  = mk2(A0.x, A0.y); w2[1]  = mk2(A0.z, A0.w);                       \
    w2[2]  = mk2(A1.x, A1.y); w2[3]  = mk2(A1.z, A1.w);                       \
    w2[4]  = mk2(A2.x, A2.y); w2[5]  = mk2(A2.z, A2.w);                       \
    w2[6]  = mk2(A3.x, A3.y); w2[7]  = mk2(A3.z, A3.w);                       \
    w2[8]  = mk2(A4.x, A4.y); w2[9]  = mk2(A4.z, A4.w);                       \
    w2[10] = mk2(A5.x, A5.y); w2[11] = mk2(A5.z, A5.w);                       \
    w2[12] = mk2(A6.x, A6.y); w2[13] = mk2(A6.z, A6.w);                       \
    w2[14] = mk2(A7.x, A7.y); w2[15] = mk2(A7.z, A7.w);                       \
    unsigned ea = u4get(ER[(tl) >> 2], (tl) & 3);                             \
    float e = __uint_as_float(ea << 16);                                      \
    float a = __uint_as_float(ea & 0xffff0000u);                              \
    f32x2 ne2 = mk2(-e, -e);                                                  \
    f32x2 a2  = mk2(a, a);                                                    \
    f32x2 r0 = mk2(0.f, 0.f), r1 = r0, r2 = r0, r3 = r0;                      \
    _Pragma("unroll")                                                         \
    for (int q = 0; q < 4; ++q) {                                             \
        r0 = fma2(w2[4*q+0], Mv2[4*q+0], r0);                                 \
        r1 = fma2(w2[4*q+1], Mv2[4*q+1], r1);                                 \
        r2 = fma2(w2[4*q+2], Mv2[4*q+2], r2);                                 \
        r3 = fma2(w2[4*q+3], Mv2[4*q+3], r3);                                 \
    }                                                                         \
    f32x2 rs = (r0 + r1) + (r2 + r3);                                         \
    slp[(tl) * RSTR + tid] = f2bf(rs.x + rs.y);                               \
    _Pragma("unroll")                                                         \
    for (int i = 0; i < 16; ++i)                                              \
        Mv2[i] = fma2(w2[i], fma2(ne2, Mv2[i], a2), Mv2[i]);                  \
} while (0)

#define SEQ_CHUNK(ER, gg, SL) do {                                            \
    const float* wlc = Wl[(gg) & 1];                                          \
    unsigned short* slp = SL;                                                 \
    PREF8(w0,w1,w2_,w3_,w4_,w5_,w6_,w7_, 0);                                  \
    _Pragma("unroll")                                                         \
    for (int tp = 0; tp < 16; ++tp) {                                         \
        SB(); PREF8(u0,u1,u2,u3,u4,u5,u6,u7, 2 * tp + 1); SB();               \
        STEP8(w0,w1,w2_,w3_,w4_,w5_,w6_,w7_, ER, 2 * tp);                     \
        SB(); PREF8(w0,w1,w2_,w3_,w4_,w5_,w6_,w7_,                            \
                    (2 * tp + 2 < 32) ? (2 * tp + 2) : 31); SB();             \
        STEP8(u0,u1,u2,u3,u4,u5,u6,u7, ER, 2 * tp + 1);                       \
    }                                                                         \
} while (0)

__device__ __forceinline__ void consume_chunk(
    int gc, const unsigned short* sl, const unsigned short* __restrict__ fWat,
    int b, int Tc, int t0,
    const unsigned short* __restrict__ Ko, const float* __restrict__ pW,
    float pbv, float* __restrict__ pred, int tid)
{
    const int lane = tid & 63;
    const int cw = (tid >> 6) & 1;          // consumer wave 0/1 -> rows cw*16..+15
    const int mrow = lane & 15, quad = lane >> 4;
    s16x8 aF[4];
#pragma unroll
    for (int kb = 0; kb < 4; ++kb)
        aF[kb] = *(const s16x8*)&sl[(cw * 16 + mrow) * RSTR + kb * 32 + quad * 8];
    float p0 = 0.f, p1 = 0.f, p2 = 0.f, p3 = 0.f;
    size_t rbase = (size_t)b * Tc + gc * CH + cw * 16 + quad * 4;
#pragma unroll
    for (int nt = 0; nt < 8; ++nt) {
        f32x4 acc = {0.f, 0.f, 0.f, 0.f};
#pragma unroll
        for (int kb = 0; kb < 4; ++kb) {
            // B-fragment direct from L2-resident global (no LDS contention)
            s16x8 bf = *(const s16x8*)&fWat[(nt * 16 + mrow) * 128 + kb * 32 + quad * 8];
            acc = __builtin_amdgcn_mfma_f32_16x16x32_bf16(aF[kb], bf, acc, 0, 0, 0);
        }
        int col = nt * 16 + mrow;
        float pw = pW[col];
        p0 = fmaf(fast_tanh(acc[0] + bf2f(Ko[(rbase + 0) * 128 + col])), pw, p0);
        p1 = fmaf(fast_tanh(acc[1] + bf2f(Ko[(rbase + 1) * 128 + col])), pw, p1);
        p2 = fmaf(fast_tanh(acc[2] + bf2f(Ko[(rbase + 2) * 128 + col])), pw, p2);
        p3 = fmaf(fast_tanh(acc[3] + bf2f(Ko[(rbase + 3) * 128 + col])), pw, p3);
    }
#pragma unroll
    for (int off = 1; off < 16; off <<= 1) {
        p0 += __shfl_xor(p0, off, 64); p1 += __shfl_xor(p1, off, 64);
        p2 += __shfl_xor(p2, off, 64); p3 += __shfl_xor(p3, off, 64);
    }
    if (mrow == 0) {
        int tb = t0 + gc * CH + cw * 16 + quad * 4;
        float ps[4] = {p0, p1, p2, p3};
#pragma unroll
        for (int reg = 0; reg < 4; ++reg) {
            int t = tb + reg;
            if (t < TT - 1) pred[b * (TT - 1) + t] = fast_sigmoid(ps[reg] + pbv);
        }
    }
}

__global__ __launch_bounds__(256, 1) void fused_kernel(
    const float* __restrict__ W, const unsigned* __restrict__ EA,
    const float* __restrict__ Mv0, const unsigned short* __restrict__ Ko,
    const unsigned short* __restrict__ fWat, const float* __restrict__ pW,
    const float* __restrict__ pb,
    float* __restrict__ pred, float* __restrict__ MvWS,
    int t0, int Tc, int doInit, int doSave)
{
    const int b = blockIdx.x;
    const int tid = threadIdx.x;
    const int nch = Tc / CH;

    __shared__ __align__(16) float Wl[2][CH * WROW];            //  9.2 KB
    __shared__ __align__(16) unsigned short rtl[2][CH * RSTR];  // 17.4 KB

    const int lr = tid >> 2, lq = tid & 3;
    const float* __restrict__ Wb = W + (size_t)b * Tc * 32;
    const uint4* __restrict__ EA4 = (const uint4*)EA;
    const int bq = b * nch;
    f32x2 Mv2[16];
    float4 wr0, wr1;
    float4 w0, w1, w2_, w3_, w4_, w5_, w6_, w7_;
    float4 u0, u1, u2, u3, u4, u5, u6, u7;
    uint4 erA[8], erB[8];
    float pbv = 0.f;

    if (tid < 128) {
        if (doInit) {
#pragma unroll
            for (int i = 0; i < 16; ++i)
                Mv2[i] = mk2(Mv0[(2 * i) * 128 + tid], Mv0[(2 * i + 1) * 128 + tid]);
        } else {
#pragma unroll
            for (int i = 0; i < 16; ++i)
                Mv2[i] = mk2(MvWS[(size_t)b * 4096 + (2 * i) * 128 + tid],
                             MvWS[(size_t)b * 4096 + (2 * i + 1) * 128 + tid]);
        }
        LOAD_W(0); PUB_W(0);
        LOAD_EA(erA, 0);
        if (nch > 1) LOAD_W(1);
    } else {
        pbv = pb[0];
    }
    __syncthreads();

    for (int g = 0; g < nch; g += 2) {
        // ---- even chunk g: produce -> slot0; consume chunk g-1 (slot1) ----
        if (tid < 128) {
            if (g + 1 < nch) PUB_W(g + 1);
            if (g + 2 < nch) LOAD_W(g + 2);
            if (g + 1 < nch) LOAD_EA(erB, g + 1);
            SEQ_CHUNK(erA, g, rtl[0]);
        } else if (g >= 1) {
            consume_chunk(g - 1, rtl[1], fWat, b, Tc, t0, Ko, pW, pbv, pred, tid);
        }
        __syncthreads();

        // ---- odd chunk g+1: produce -> slot1; consume chunk g (slot0) ----
        if (tid < 128) {
            if (g + 1 < nch) {
                if (g + 2 < nch) PUB_W(g + 2);
                if (g + 3 < nch) LOAD_W(g + 3);
                if (g + 2 < nch) LOAD_EA(erA, g + 2);
                SEQ_CHUNK(erB, g + 1, rtl[1]);
            }
        } else {
            consume_chunk(g, rtl[0], fWat, b, Tc, t0, Ko, pW, pbv, pred, tid);
        }
        __syncthreads();
    }
    // epilogue: for even nch the last (odd) chunk is still unconsumed
    if (!(nch & 1) && tid >= 128) {
        consume_chunk(nch - 1, rtl[1], fWat, b, Tc, t0, Ko, pW, pbv, pred, tid);
    }

    if (doSave && tid < 128) {
#pragma unroll
        for (int i = 0; i < 16; ++i) {
            MvWS[(size_t)b * 4096 + (2 * i) * 128 + tid]     = Mv2[i].x;
            MvWS[(size_t)b * 4096 + (2 * i + 1) * 128 + tid] = Mv2[i].y;
        }
    }
}

// ---------------------------------------------------------------------------

extern "C" void kernel_launch(void* const* d_in, const int* in_sizes, int n_in,
                              void* d_out, int out_size, void* d_ws, size_t ws_size,
                              hipStream_t stream) {
    const int*   skills    = (const int*)d_in[0];
    const int*   responses = (const int*)d_in[1];
    const float* k_emb     = (const float*)d_in[2];
    const float* v_emb     = (const float*)d_in[3];
    const float* Mk        = (const float*)d_in[4];
    const float* Mv0       = (const float*)d_in[5];
    const float* f_W       = (const float*)d_in[6];
    const float* f_b       = (const float*)d_in[7];
    const float* p_W       = (const float*)d_in[8];
    const float* p_b       = (const float*)d_in[9];
    const float* e_W       = (const float*)d_in[10];
    const float* e_b       = (const float*)d_in[11];
    const float* a_W       = (const float*)d_in[12];
    const float* a_b       = (const float*)d_in[13];

    float* pred    = (float*)d_out;                 // [256][255]
    float* outTrue = pred + BB * (TT - 1);          // [256][255]

    // scratch per row: Wo 128 B + EA 512 B + Ko 256 B = 896 B
    int Tc = TT;
    for (;;) {
        size_t need = (size_t)BB * Tc * 896 + 69632 * 2;
        if (Tc < TT) need += (size_t)BB * 4096 * 4;
        if (need <= ws_size || Tc <= 32) break;
        Tc >>= 1;
    }

    char* p = (char*)d_ws;
    float* Wo = (float*)p;                     p += (size_t)BB * Tc * 32 * 4;
    unsigned* EA = (unsigned*)p;               p += (size_t)BB * Tc * 128 * 4;
    unsigned short* Ko = (unsigned short*)p;   p += (size_t)BB * Tc * 128 * 2;
    unsigned short* eWt = (unsigned short*)p;  p += 16384 * 2;
    unsigned short* aWt = (unsigned short*)p;  p += 16384 * 2;
    unsigned short* fWat = (unsigned short*)p; p += 16384 * 2;
    unsigned short* fWbt = (unsigned short*)p; p += 16384 * 2;
    unsigned short* Mkt = (unsigned short*)p;  p += 4096 * 2;
    float* MvWS = (float*)p;

    conv_kernel<<<272, 256, 0, stream>>>(e_W, a_W, f_W, Mk,
                                         eWt, aWt, fWat, fWbt, Mkt);

    for (int t0 = 0; t0 < TT; t0 += Tc) {
        pre_kernel<<<(BB * Tc) / 64, 256, 0, stream>>>(
            skills, responses, k_emb, v_emb, f_b, e_b, a_b,
            Mkt, fWbt, eWt, aWt, Wo, EA, Ko, outTrue, t0, Tc);
        fused_kernel<<<BB, 256, 0, stream>>>(
            Wo, EA, Mv0, Ko, fWat, p_W, p_b, pred, MvWS,
            t0, Tc, t0 == 0 ? 1 : 0, (t0 + Tc < TT) ? 1 : 0);
    }
}

// Round 15
// 164.955 us; speedup vs baseline: 1.1863x; 1.0962x over previous
//
#include <hip/hip_runtime.h>
#include <math.h>

// Problem constants (fixed by setup_inputs)
#define BB 256      // batch
#define TT 256      // time steps
#define NQ 1000     // num_q
#define DK 128
#define DV 128
#define CC 32

typedef short s16x8 __attribute__((ext_vector_type(8)));   // 8 bf16 bit-patterns
typedef float f32x4 __attribute__((ext_vector_type(4)));
typedef float f32x2 __attribute__((ext_vector_type(2)));

__device__ __forceinline__ float fast_sigmoid(float x) {
    x = fminf(fmaxf(x, -30.f), 30.f);
    return 1.f / (1.f + __expf(-x));
}
__device__ __forceinline__ float fast_tanh(float x) {
    x = fminf(fmaxf(x, -15.f), 15.f);
    float t = __expf(2.f * x);
    return (t - 1.f) / (t + 1.f);
}
__device__ __forceinline__ unsigned short f2bf(float f) {   // RNE fp32->bf16
    unsigned u = __float_as_uint(f);
    u += 0x7fffu + ((u >> 16) & 1u);
    return (unsigned short)(u >> 16);
}
__device__ __forceinline__ float bf2f(unsigned short h) {
    return __uint_as_float((unsigned)h << 16);
}
__device__ __forceinline__ unsigned u4get(uint4 v, int i) { // i constant after unroll
    return i == 0 ? v.x : i == 1 ? v.y : i == 2 ? v.z : v.w;
}
__device__ __forceinline__ f32x2 mk2(float x, float y) { f32x2 r; r.x = x; r.y = y; return r; }
__device__ __forceinline__ f32x2 fma2(f32x2 a, f32x2 b, f32x2 c) {
    return __builtin_elementwise_fma(a, b, c);
}
__device__ __forceinline__ s16x8 cvt8(float4 v0, float4 v1) {
    s16x8 f;
    f[0] = (short)f2bf(v0.x); f[1] = (short)f2bf(v0.y);
    f[2] = (short)f2bf(v0.z); f[3] = (short)f2bf(v0.w);
    f[4] = (short)f2bf(v1.x); f[5] = (short)f2bf(v1.y);
    f[6] = (short)f2bf(v1.z); f[7] = (short)f2bf(v1.w);
    return f;
}

// ---------------------------------------------------------------------------
// conv_kernel: build bf16 TRANSPOSED weights in ws (B-operand layout Wt[n][k])
// ---------------------------------------------------------------------------
__global__ __launch_bounds__(256) void conv_kernel(
    const float* __restrict__ eW, const float* __restrict__ aW,
    const float* __restrict__ fW, const float* __restrict__ Mk,
    unsigned short* __restrict__ eWt, unsigned short* __restrict__ aWt,
    unsigned short* __restrict__ fWat, unsigned short* __restrict__ fWbt,
    unsigned short* __restrict__ Mkt)
{
    int idx = blockIdx.x * 256 + threadIdx.x;
    if (idx < 16384) {
        int n = idx >> 7, k = idx & 127;
        eWt[idx] = f2bf(eW[k * 128 + n]);
    } else if (idx < 32768) {
        int i = idx - 16384; int n = i >> 7, k = i & 127;
        aWt[i] = f2bf(aW[k * 128 + n]);
    } else if (idx < 49152) {
        int i = idx - 32768; int n = i >> 7, k = i & 127;
        fWat[i] = f2bf(fW[k * 128 + n]);
    } else if (idx < 65536) {
        int i = idx - 49152; int n = i >> 7, k = i & 127;
        fWbt[i] = f2bf(fW[(128 + k) * 128 + n]);
    } else if (idx < 69632) {
        int i = idx - 65536; int n = i >> 7, k = i & 127;   // n=c 0..31
        Mkt[i] = f2bf(Mk[k * 32 + n]);
    }
}

// ---------------------------------------------------------------------------
// pre_kernel v2 (R11 — measured optimum ~37 us): Wlds staging + direct-to-
// fragment gathers + in-register softmax + et parked in registers.
// R13 (LDS-free) measured 69 us — staged LDS B-frags win.
// ---------------------------------------------------------------------------
__global__ __launch_bounds__(256) void pre_kernel(
    const int* __restrict__ skills, const int* __restrict__ responses,
    const float* __restrict__ k_emb, const float* __restrict__ v_emb,
    const float* __restrict__ fb, const float* __restrict__ eb,
    const float* __restrict__ ab,
    const unsigned short* __restrict__ Mkt, const unsigned short* __restrict__ fWbt,
    const unsigned short* __restrict__ eWt, const unsigned short* __restrict__ aWt,
    float* __restrict__ Wo, unsigned* __restrict__ EA,
    unsigned short* __restrict__ Ko, float* __restrict__ outTrue,
    int t0, int Tc)
{
    const int tid = threadIdx.x;
    const int lane = tid & 63;
    const int m_base = (tid >> 6) * 16;
    const int mrow = lane & 15, quad = lane >> 4;
    const size_t base = (size_t)blockIdx.x * 64;

    __shared__ __align__(16) unsigned short Wlds[128 * 136];   // 34.8 KB

    int grow = (int)base + m_base + mrow;
    int gb = grow / Tc;
    int gt = t0 + (grow - gb * Tc);
    int gi = gb * TT + gt;
    int s = skills[gi];
    int r = responses[gi];
    int q = s + NQ * ((r > -1) ? r : 0);
    if (quad == 0 && gt >= 1) outTrue[gb * (TT - 1) + (gt - 1)] = (float)r;

    {
        int n = tid >> 3, k0 = (tid & 7) * 16;
        *(s16x8*)&Wlds[n * 136 + k0]     = *(const s16x8*)&Mkt[n * 128 + k0];
        *(s16x8*)&Wlds[n * 136 + k0 + 8] = *(const s16x8*)&Mkt[n * 128 + k0 + 8];
    }

    s16x8 aF[4];
    {
        const float* kr = k_emb + (size_t)s * DK + quad * 8;
#pragma unroll
        for (int kb = 0; kb < 4; ++kb)
            aF[kb] = cvt8(*(const float4*)(kr + kb * 32),
                          *(const float4*)(kr + kb * 32 + 4));
    }
    __syncthreads();   // [1]

    {
        f32x4 l0 = {0.f, 0.f, 0.f, 0.f}, l1 = {0.f, 0.f, 0.f, 0.f};
#pragma unroll
        for (int kb = 0; kb < 4; ++kb) {
            s16x8 b0 = *(const s16x8*)&Wlds[mrow * 136 + kb * 32 + quad * 8];
            s16x8 b1 = *(const s16x8*)&Wlds[(16 + mrow) * 136 + kb * 32 + quad * 8];
            l0 = __builtin_amdgcn_mfma_f32_16x16x32_bf16(aF[kb], b0, l0, 0, 0, 0);
            l1 = __builtin_amdgcn_mfma_f32_16x16x32_bf16(aF[kb], b1, l1, 0, 0, 0);
        }
#pragma unroll
        for (int reg = 0; reg < 4; ++reg) {
            float a0 = l0[reg], a1 = l1[reg];
            float m = fmaxf(a0, a1);
#pragma unroll
            for (int off = 1; off < 16; off <<= 1)
                m = fmaxf(m, __shfl_xor(m, off, 64));
            float e0 = __expf(a0 - m), e1 = __expf(a1 - m);
            float ssum = e0 + e1;
#pragma unroll
            for (int off = 1; off < 16; off <<= 1)
                ssum += __shfl_xor(ssum, off, 64);
            float inv = 1.f / ssum;
            size_t rowg = base + m_base + quad * 4 + reg;
            Wo[rowg * 32 + mrow]      = e0 * inv;
            Wo[rowg * 32 + 16 + mrow] = e1 * inv;
        }
    }
    __syncthreads();   // [2]

    {
        int n = tid >> 1, k0 = (tid & 1) * 64;
#pragma unroll
        for (int j = 0; j < 8; ++j)
            *(s16x8*)&Wlds[n * 136 + k0 + j * 8] = *(const s16x8*)&fWbt[n * 128 + k0 + j * 8];
    }
    __syncthreads();   // [3]

    s16x8 vF[4];
    {
        const float* vr = v_emb + (size_t)q * DV + quad * 8;
#pragma unroll
        for (int kb = 0; kb < 4; ++kb)
            vF[kb] = cvt8(*(const float4*)(vr + kb * 32),
                          *(const float4*)(vr + kb * 32 + 4));
    }

#pragma unroll
    for (int nt = 0; nt < 8; ++nt) {
        f32x4 acc = {0.f, 0.f, 0.f, 0.f};
#pragma unroll
        for (int kb = 0; kb < 4; ++kb) {
            s16x8 bf = *(const s16x8*)&Wlds[(nt * 16 + mrow) * 136 + kb * 32 + quad * 8];
            acc = __builtin_amdgcn_mfma_f32_16x16x32_bf16(aF[kb], bf, acc, 0, 0, 0);
        }
        int col = nt * 16 + mrow;
        float fbv = fb[col];
#pragma unroll
        for (int reg = 0; reg < 4; ++reg) {
            size_t rr = base + m_base + quad * 4 + reg;
            Ko[rr * 128 + col] = f2bf(acc[reg] + fbv);
        }
    }
    __syncthreads();   // [4]

    {
        int n = tid >> 1, k0 = (tid & 1) * 64;
#pragma unroll
        for (int j = 0; j < 8; ++j)
            *(s16x8*)&Wlds[n * 136 + k0 + j * 8] = *(const s16x8*)&eWt[n * 128 + k0 + j * 8];
    }
    __syncthreads();   // [5]

    float etr[8][4];
#pragma unroll
    for (int nt = 0; nt < 8; ++nt) {
        f32x4 acc = {0.f, 0.f, 0.f, 0.f};
#pragma unroll
        for (int kb = 0; kb < 4; ++kb) {
            s16x8 bf = *(const s16x8*)&Wlds[(nt * 16 + mrow) * 136 + kb * 32 + quad * 8];
            acc = __builtin_amdgcn_mfma_f32_16x16x32_bf16(vF[kb], bf, acc, 0, 0, 0);
        }
        int col = nt * 16 + mrow;
        float ebv = eb[col];
#pragma unroll
        for (int reg = 0; reg < 4; ++reg)
            etr[nt][reg] = fast_sigmoid(acc[reg] + ebv);
    }
    __syncthreads();   // [6]

    {
        int n = tid >> 1, k0 = (tid & 1) * 64;
#pragma unroll
        for (int j = 0; j < 8; ++j)
            *(s16x8*)&Wlds[n * 136 + k0 + j * 8] = *(const s16x8*)&aWt[n * 128 + k0 + j * 8];
    }
    __syncthreads();   // [7]

#pragma unroll
    for (int nt = 0; nt < 8; ++nt) {
        f32x4 acc = {0.f, 0.f, 0.f, 0.f};
#pragma unroll
        for (int kb = 0; kb < 4; ++kb) {
            s16x8 bf = *(const s16x8*)&Wlds[(nt * 16 + mrow) * 136 + kb * 32 + quad * 8];
            acc = __builtin_amdgcn_mfma_f32_16x16x32_bf16(vF[kb], bf, acc, 0, 0, 0);
        }
        int col = nt * 16 + mrow;
        float abv = ab[col];
#pragma unroll
        for (int reg = 0; reg < 4; ++reg) {
            size_t rr = base + m_base + quad * 4 + reg;
            int bb = (int)(rr / (size_t)Tc);
            int t  = (int)(rr - (size_t)bb * Tc);
            size_t o4 = (((size_t)bb * (Tc >> 5) + (t >> 5)) * 8 + ((t >> 2) & 7)) * 128 + col;
            unsigned lo = f2bf(etr[nt][reg]);
            unsigned hi = (unsigned)f2bf(fast_tanh(acc[reg] + abv)) << 16;
            EA[o4 * 4 + (t & 3)] = hi | lo;
        }
    }
}

// ---------------------------------------------------------------------------
// fused_kernel v5 (seq + post) — EXACT R11 form (measured optimum 54.7 us).
// R14's consumer-global-B-frag variant measured 69 us: consumer frags belong
// in LDS. Producer w stays on the LDS broadcast path (R12 scalar/global
// attempt: 75 us). Pipelining attempts R8/R10/R11-fence all collapsed by
// the toolchain — load-at-use + compiler lgkmcnt is the floor here.
// ---------------------------------------------------------------------------

#define CH 32
#define WROW 36     // Wl row stride (floats)
#define RSTR 136    // rtl/fWl row stride (shorts)
#define SB() __builtin_amdgcn_sched_barrier(0)

#define LOAD_W(gg) do {                                                       \
    const float* ws = Wb + (size_t)(gg) * CH * 32;                            \
    wr0 = *(const float4*)(ws + tid * 8);                                     \
    wr1 = *(const float4*)(ws + tid * 8 + 4);                                 \
} while (0)

#define PUB_W(gg) do {                                                        \
    float* wd = &Wl[(gg) & 1][lr * WROW + lq * 8];                            \
    *(float4*)wd = wr0; *(float4*)(wd + 4) = wr1;                             \
} while (0)

#define LOAD_EA(ER, gg) do {                                                  \
    const uint4* src = EA4 + ((size_t)(bq + (gg))) * 1024 + tid;              \
    _Pragma("unroll")                                                         \
    for (int j = 0; j < 8; ++j) ER[j] = src[j * 128];                         \
} while (0)

#define PREF8(A0,A1,A2,A3,A4,A5,A6,A7, rowidx) do {                           \
    const float* _wr = wlc + (rowidx) * WROW;                                 \
    A0 = *(const float4*)(_wr + 0);  A1 = *(const float4*)(_wr + 4);          \
    A2 = *(const float4*)(_wr + 8);  A3 = *(const float4*)(_wr + 12);         \
    A4 = *(const float4*)(_wr + 16); A5 = *(const float4*)(_wr + 20);         \
    A6 = *(const float4*)(_wr + 24); A7 = *(const float4*)(_wr + 28);         \
} while (0)

#define STEP8(A0,A1,A2,A3,A4,A5,A6,A7, ER, tl) do {                           \
    f32x2 w2[16];                                                             \
    w2[0]  = mk2(A0.x, A0.y); w2[1]  = mk2(A0.z, A0.w);                       \
    w2[2]  = mk2(A1.x, A1.y); w2[3]  = mk2(A1.z, A1.w);                       \
    w2[4]  = mk2(A2.x, A2.y); w2[5]  = mk2(A2.z, A2.w);                       \
    w2[6]  = mk2(A3.x, A3.y); w2[7]  = mk2(A3.z, A3.w);                       \
    w2[8]  = mk2(A4.x, A4.y); w2[9]  = mk2(A4.z, A4.w);                       \
    w2[10] = mk2(A5.x, A5.y); w2[11] = mk2(A5.z, A5.w);                       \
    w2[12] = mk2(A6.x, A6.y); w2[13] = mk2(A6.z, A6.w);                       \
    w2[14] = mk2(A7.x, A7.y); w2[15] = mk2(A7.z, A7.w);                       \
    unsigned ea = u4get(ER[(tl) >> 2], (tl) & 3);                             \
    float e = __uint_as_float(ea << 16);                                      \
    float a = __uint_as_float(ea & 0xffff0000u);                              \
    f32x2 ne2 = mk2(-e, -e);                                                  \
    f32x2 a2  = mk2(a, a);                                                    \
    f32x2 r0 = mk2(0.f, 0.f), r1 = r0, r2 = r0, r3 = r0;                      \
    _Pragma("unroll")                                                         \
    for (int q = 0; q < 4; ++q) {                                             \
        r0 = fma2(w2[4*q+0], Mv2[4*q+0], r0);                                 \
        r1 = fma2(w2[4*q+1], Mv2[4*q+1], r1);                                 \
        r2 = fma2(w2[4*q+2], Mv2[4*q+2], r2);                                 \
        r3 = fma2(w2[4*q+3], Mv2[4*q+3], r3);                                 \
    }                                                                         \
    f32x2 rs = (r0 + r1) + (r2 + r3);                                         \
    slp[(tl) * RSTR + tid] = f2bf(rs.x + rs.y);                               \
    _Pragma("unroll")                                                         \
    for (int i = 0; i < 16; ++i)                                              \
        Mv2[i] = fma2(w2[i], fma2(ne2, Mv2[i], a2), Mv2[i]);                  \
} while (0)

#define SEQ_CHUNK(ER, gg, SL) do {                                            \
    const float* wlc = Wl[(gg) & 1];                                          \
    unsigned short* slp = SL;                                                 \
    PREF8(w0,w1,w2_,w3_,w4_,w5_,w6_,w7_, 0);                                  \
    _Pragma("unroll")                                                         \
    for (int tp = 0; tp < 16; ++tp) {                                         \
        SB(); PREF8(u0,u1,u2,u3,u4,u5,u6,u7, 2 * tp + 1); SB();               \
        STEP8(w0,w1,w2_,w3_,w4_,w5_,w6_,w7_, ER, 2 * tp);                     \
        SB(); PREF8(w0,w1,w2_,w3_,w4_,w5_,w6_,w7_,                            \
                    (2 * tp + 2 < 32) ? (2 * tp + 2) : 31); SB();             \
        STEP8(u0,u1,u2,u3,u4,u5,u6,u7, ER, 2 * tp + 1);                       \
    }                                                                         \
} while (0)

__device__ __forceinline__ void consume_chunk(
    int gc, const unsigned short* sl, const unsigned short* fWl,
    int b, int Tc, int t0,
    const unsigned short* __restrict__ Ko, const float* __restrict__ pW,
    float pbv, float* __restrict__ pred, int tid)
{
    const int lane = tid & 63;
    const int cw = (tid >> 6) & 1;          // consumer wave 0/1 -> rows cw*16..+15
    const int mrow = lane & 15, quad = lane >> 4;
    s16x8 aF[4];
#pragma unroll
    for (int kb = 0; kb < 4; ++kb)
        aF[kb] = *(const s16x8*)&sl[(cw * 16 + mrow) * RSTR + kb * 32 + quad * 8];
    float p0 = 0.f, p1 = 0.f, p2 = 0.f, p3 = 0.f;
    size_t rbase = (size_t)b * Tc + gc * CH + cw * 16 + quad * 4;
#pragma unroll
    for (int nt = 0; nt < 8; ++nt) {
        f32x4 acc = {0.f, 0.f, 0.f, 0.f};
#pragma unroll
        for (int kb = 0; kb < 4; ++kb) {
            s16x8 bf = *(const s16x8*)&fWl[(nt * 16 + mrow) * RSTR + kb * 32 + quad * 8];
            acc = __builtin_amdgcn_mfma_f32_16x16x32_bf16(aF[kb], bf, acc, 0, 0, 0);
        }
        int col = nt * 16 + mrow;
        float pw = pW[col];
        p0 = fmaf(fast_tanh(acc[0] + bf2f(Ko[(rbase + 0) * 128 + col])), pw, p0);
        p1 = fmaf(fast_tanh(acc[1] + bf2f(Ko[(rbase + 1) * 128 + col])), pw, p1);
        p2 = fmaf(fast_tanh(acc[2] + bf2f(Ko[(rbase + 2) * 128 + col])), pw, p2);
        p3 = fmaf(fast_tanh(acc[3] + bf2f(Ko[(rbase + 3) * 128 + col])), pw, p3);
    }
#pragma unroll
    for (int off = 1; off < 16; off <<= 1) {
        p0 += __shfl_xor(p0, off, 64); p1 += __shfl_xor(p1, off, 64);
        p2 += __shfl_xor(p2, off, 64); p3 += __shfl_xor(p3, off, 64);
    }
    if (mrow == 0) {
        int tb = t0 + gc * CH + cw * 16 + quad * 4;
        float ps[4] = {p0, p1, p2, p3};
#pragma unroll
        for (int reg = 0; reg < 4; ++reg) {
            int t = tb + reg;
            if (t < TT - 1) pred[b * (TT - 1) + t] = fast_sigmoid(ps[reg] + pbv);
        }
    }
}

__global__ __launch_bounds__(256, 1) void fused_kernel(
    const float* __restrict__ W, const unsigned* __restrict__ EA,
    const float* __restrict__ Mv0, const unsigned short* __restrict__ Ko,
    const unsigned short* __restrict__ fWat, const float* __restrict__ pW,
    const float* __restrict__ pb,
    float* __restrict__ pred, float* __restrict__ MvWS,
    int t0, int Tc, int doInit, int doSave)
{
    const int b = blockIdx.x;
    const int tid = threadIdx.x;
    const int nch = Tc / CH;

    __shared__ __align__(16) float Wl[2][CH * WROW];            //  9.2 KB
    __shared__ __align__(16) unsigned short rtl[2][CH * RSTR];  // 17.4 KB
    __shared__ __align__(16) unsigned short fWl[128 * RSTR];    // 34.8 KB

    // stage fWat -> fWl (all 256 threads)
    {
        int n = tid >> 1, k0 = (tid & 1) * 64;
#pragma unroll
        for (int j = 0; j < 8; ++j)
            *(s16x8*)&fWl[n * RSTR + k0 + j * 8] = *(const s16x8*)&fWat[n * 128 + k0 + j * 8];
    }

    const int lr = tid >> 2, lq = tid & 3;
    const float* __restrict__ Wb = W + (size_t)b * Tc * 32;
    const uint4* __restrict__ EA4 = (const uint4*)EA;
    const int bq = b * nch;
    f32x2 Mv2[16];
    float4 wr0, wr1;
    float4 w0, w1, w2_, w3_, w4_, w5_, w6_, w7_;
    float4 u0, u1, u2, u3, u4, u5, u6, u7;
    uint4 erA[8], erB[8];
    float pbv = 0.f;

    if (tid < 128) {
        if (doInit) {
#pragma unroll
            for (int i = 0; i < 16; ++i)
                Mv2[i] = mk2(Mv0[(2 * i) * 128 + tid], Mv0[(2 * i + 1) * 128 + tid]);
        } else {
#pragma unroll
            for (int i = 0; i < 16; ++i)
                Mv2[i] = mk2(MvWS[(size_t)b * 4096 + (2 * i) * 128 + tid],
                             MvWS[(size_t)b * 4096 + (2 * i + 1) * 128 + tid]);
        }
        LOAD_W(0); PUB_W(0);
        LOAD_EA(erA, 0);
        if (nch > 1) LOAD_W(1);
    } else {
        pbv = pb[0];
    }
    __syncthreads();

    for (int g = 0; g < nch; g += 2) {
        // ---- even chunk g: produce -> slot0; consume chunk g-1 (slot1) ----
        if (tid < 128) {
            if (g + 1 < nch) PUB_W(g + 1);
            if (g + 2 < nch) LOAD_W(g + 2);
            if (g + 1 < nch) LOAD_EA(erB, g + 1);
            SEQ_CHUNK(erA, g, rtl[0]);
        } else if (g >= 1) {
            consume_chunk(g - 1, rtl[1], fWl, b, Tc, t0, Ko, pW, pbv, pred, tid);
        }
        __syncthreads();

        // ---- odd chunk g+1: produce -> slot1; consume chunk g (slot0) ----
        if (tid < 128) {
            if (g + 1 < nch) {
                if (g + 2 < nch) PUB_W(g + 2);
                if (g + 3 < nch) LOAD_W(g + 3);
                if (g + 2 < nch) LOAD_EA(erA, g + 2);
                SEQ_CHUNK(erB, g + 1, rtl[1]);
            }
        } else {
            consume_chunk(g, rtl[0], fWl, b, Tc, t0, Ko, pW, pbv, pred, tid);
        }
        __syncthreads();
    }
    // epilogue: for even nch the last (odd) chunk is still unconsumed
    if (!(nch & 1) && tid >= 128) {
        consume_chunk(nch - 1, rtl[1], fWl, b, Tc, t0, Ko, pW, pbv, pred, tid);
    }

    if (doSave && tid < 128) {
#pragma unroll
        for (int i = 0; i < 16; ++i) {
            MvWS[(size_t)b * 4096 + (2 * i) * 128 + tid]     = Mv2[i].x;
            MvWS[(size_t)b * 4096 + (2 * i + 1) * 128 + tid] = Mv2[i].y;
        }
    }
}

// ---------------------------------------------------------------------------

extern "C" void kernel_launch(void* const* d_in, const int* in_sizes, int n_in,
                              void* d_out, int out_size, void* d_ws, size_t ws_size,
                              hipStream_t stream) {
    const int*   skills    = (const int*)d_in[0];
    const int*   responses = (const int*)d_in[1];
    const float* k_emb     = (const float*)d_in[2];
    const float* v_emb     = (const float*)d_in[3];
    const float* Mk        = (const float*)d_in[4];
    const float* Mv0       = (const float*)d_in[5];
    const float* f_W       = (const float*)d_in[6];
    const float* f_b       = (const float*)d_in[7];
    const float* p_W       = (const float*)d_in[8];
    const float* p_b       = (const float*)d_in[9];
    const float* e_W       = (const float*)d_in[10];
    const float* e_b       = (const float*)d_in[11];
    const float* a_W       = (const float*)d_in[12];
    const float* a_b       = (const float*)d_in[13];

    float* pred    = (float*)d_out;                 // [256][255]
    float* outTrue = pred + BB * (TT - 1);          // [256][255]

    // scratch per row: Wo 128 B + EA 512 B + Ko 256 B = 896 B
    int Tc = TT;
    for (;;) {
        size_t need = (size_t)BB * Tc * 896 + 69632 * 2;
        if (Tc < TT) need += (size_t)BB * 4096 * 4;
        if (need <= ws_size || Tc <= 32) break;
        Tc >>= 1;
    }

    char* p = (char*)d_ws;
    float* Wo = (float*)p;                     p += (size_t)BB * Tc * 32 * 4;
    unsigned* EA = (unsigned*)p;               p += (size_t)BB * Tc * 128 * 4;
    unsigned short* Ko = (unsigned short*)p;   p += (size_t)BB * Tc * 128 * 2;
    unsigned short* eWt = (unsigned short*)p;  p += 16384 * 2;
    unsigned short* aWt = (unsigned short*)p;  p += 16384 * 2;
    unsigned short* fWat = (unsigned short*)p; p += 16384 * 2;
    unsigned short* fWbt = (unsigned short*)p; p += 16384 * 2;
    unsigned short* Mkt = (unsigned short*)p;  p += 4096 * 2;
    float* MvWS = (float*)p;

    conv_kernel<<<272, 256, 0, stream>>>(e_W, a_W, f_W, Mk,
                                         eWt, aWt, fWat, fWbt, Mkt);

    for (int t0 = 0; t0 < TT; t0 += Tc) {
        pre_kernel<<<(BB * Tc) / 64, 256, 0, stream>>>(
            skills, responses, k_emb, v_emb, f_b, e_b, a_b,
            Mkt, fWbt, eWt, aWt, Wo, EA, Ko, outTrue, t0, Tc);
        fused_kernel<<<BB, 256, 0, stream>>>(
            Wo, EA, Mv0, Ko, fWat, p_W, p_b, pred, MvWS,
            t0, Tc, t0 == 0 ? 1 : 0, (t0 + Tc < TT) ? 1 : 0);
    }
}